// Round 7
// baseline (632.137 us; speedup 1.0000x reference)
//
#include <hip/hip_runtime.h>
#include <hip/hip_bf16.h>

// Problem constants
#define D_MODEL 768
#define SEQL    2048
#define BATCH   8
#define NSTATE  16
#define NCHUNK  32
#define TCHUNK  64   // SEQL / NCHUNK

typedef __attribute__((ext_vector_type(8))) short short8;
typedef __attribute__((ext_vector_type(4))) float f32x4;

typedef const __attribute__((address_space(1))) unsigned int gas1_t;
typedef __attribute__((address_space(3))) unsigned int las3_t;

__device__ __forceinline__ void gload_lds16(const void* g, void* l) {
  __builtin_amdgcn_global_load_lds((gas1_t*)g, (las3_t*)l, 16, 0, 0);
}

__device__ __forceinline__ float b2f(short s) {
  return __uint_as_float(((unsigned)(unsigned short)s) << 16);
}
__device__ __forceinline__ short f2b(float f) {
  __hip_bfloat16 h = __float2bfloat16(f);
  return *reinterpret_cast<short*>(&h);
}

// ---------------------------------------------------------------------------
// Merged prep: x -> bf16 (x4/thread), weights -> bf16 (dbc 896 rows), A2.
// ---------------------------------------------------------------------------
__global__ __launch_bounds__(256) void prep_all(
    const float* __restrict__ x, const float* __restrict__ in_w,
    const float* __restrict__ delta_w, const float* __restrict__ Bp,
    const float* __restrict__ Cp, const float* __restrict__ out_w,
    const float* __restrict__ A_log,
    __hip_bfloat16* __restrict__ xb, __hip_bfloat16* __restrict__ w_in,
    __hip_bfloat16* __restrict__ w_dbc, __hip_bfloat16* __restrict__ w_out,
    float* __restrict__ A2) {
  int i = blockIdx.x * 256 + threadIdx.x;
  if (i < 3145728) {
    int j = i * 4;
    float4 v = *(const float4*)(x + j);
    xb[j + 0] = __float2bfloat16(v.x);
    xb[j + 1] = __float2bfloat16(v.y);
    xb[j + 2] = __float2bfloat16(v.z);
    xb[j + 3] = __float2bfloat16(v.w);
    return;
  }
  i -= 3145728;
  if (i < 1536 * 768) { w_in[i] = __float2bfloat16(in_w[i]); return; }
  i -= 1536 * 768;
  if (i < 896 * 768) {   // 896 rows = 768 delta + 16 B + 16 C + 96 pad
    int row = i / 768, col = i - row * 768;
    float v;
    if (row < 768)      v = delta_w[row * 768 + col];
    else if (row < 784) v = Bp[(row - 768) * 768 + col];
    else if (row < 800) v = Cp[(row - 784) * 768 + col];
    else                v = 0.f;
    w_dbc[i] = __float2bfloat16(v);
    return;
  }
  i -= 896 * 768;
  if (i < 768 * 768) { w_out[i] = __float2bfloat16(out_w[i]); return; }
  i -= 768 * 768;
  A2[i] = -expf(A_log[i]) * 1.44269504088896f;  // A * log2(e)
}

// ---------------------------------------------------------------------------
// Production GEMM (R6 config, unchanged): 128x128 tile, BK=32, 4 waves,
// 3 bufs x 16KB = 48KB LDS -> 3 blocks/CU.  Counted vmcnt(4), 2-lane/bank
// swizzle, bijective XCD swizzle.
// ---------------------------------------------------------------------------
template <int MODE>
__global__ __launch_bounds__(256, 3) void gemm128tb(
    const __hip_bfloat16* __restrict__ Amat, const __hip_bfloat16* __restrict__ Bw,
    const float* __restrict__ bias, void* __restrict__ out0,
    void* __restrict__ out1, void* __restrict__ out2, const int gxn) {
  constexpr int K  = 768;
  constexpr int KT = 24;           // K / 32
  __shared__ char lds[49152];      // 3 x 16KB
  const int tid  = threadIdx.x;
  const int lane = tid & 63, wave = tid >> 6;
  const int wr = wave >> 1, wc = wave & 1;

  const int nwg = gridDim.x, id = blockIdx.x;
  const int swz = (id & 7) * (nwg >> 3) + (id >> 3);
  const int tm = swz / gxn, tn = swz - tm * gxn;
  const int rowA0 = tm * 128, rowB0 = tn * 128;

  const int srow = tid >> 2;                                   // 0..63
  const int scol = (((tid & 3) ^ ((srow >> 1) & 3)) << 3);     // elem col
  const __hip_bfloat16* gA = Amat + (size_t)(rowA0 + srow) * K + scol;
  const __hip_bfloat16* gB = Bw   + (size_t)(rowB0 + srow) * K + scol;
  const int ldst = tid << 4;

  const int frow = lane & 15, fq = lane >> 4;
  const int pc = (fq << 4) ^ (((frow >> 1) & 3) << 4);
  const int aoff = ((wr * 64 + frow) << 6) + pc;   // 64B rows
  const int boff = ((wc * 64 + frow) << 6) + pc;

  f32x4 acc[4][4];
#pragma unroll
  for (int m = 0; m < 4; ++m)
#pragma unroll
    for (int n = 0; n < 4; ++n) acc[m][n] = (f32x4){0.f, 0.f, 0.f, 0.f};

#define STAGE(buf, kt)                                                          \
  {                                                                             \
    const __hip_bfloat16* sA = gA + (kt) * 32;                                  \
    const __hip_bfloat16* sB = gB + (kt) * 32;                                  \
    char* dA = lds + (buf) * 16384 + ldst;                                      \
    char* dB = dA + 8192;                                                       \
    gload_lds16(sA, dA);                                                        \
    gload_lds16(sA + (size_t)64 * K, dA + 4096);                                \
    gload_lds16(sB, dB);                                                        \
    gload_lds16(sB + (size_t)64 * K, dB + 4096);                                \
  }
#define VMW(n) asm volatile("s_waitcnt vmcnt(" #n ")" ::: "memory")
#define BAR    __builtin_amdgcn_s_barrier()

  STAGE(0, 0);
  STAGE(1, 1);
  VMW(4);
  BAR;

  int bc = 0;  // current buffer = kt % 3
  for (int kt = 0; kt < KT; ++kt) {
    short8 a[4], b[4];
    const char* ba = lds + bc * 16384;
#pragma unroll
    for (int m = 0; m < 4; ++m) a[m] = *(const short8*)(ba + aoff + m * 1024);
#pragma unroll
    for (int n = 0; n < 4; ++n) b[n] = *(const short8*)(ba + 8192 + boff + n * 1024);
    const bool st = (kt + 2 < KT);
    if (st) {
      const int b2 = bc + 2 >= 3 ? bc - 1 : bc + 2;
      STAGE(b2, kt + 2);
    }
    __builtin_amdgcn_s_setprio(1);
#pragma unroll
    for (int m = 0; m < 4; ++m)
#pragma unroll
      for (int n = 0; n < 4; ++n)
        acc[m][n] = __builtin_amdgcn_mfma_f32_16x16x32_bf16(a[m], b[n], acc[m][n], 0, 0, 0);
    __builtin_amdgcn_s_setprio(0);
    if (st)                VMW(4);
    else if (kt + 2 == KT) VMW(0);
    BAR;
    bc = bc + 1 >= 3 ? 0 : bc + 1;
  }

#pragma unroll
  for (int m = 0; m < 4; ++m) {
    const int grow0 = rowA0 + wr * 64 + m * 16 + fq * 4;
#pragma unroll
    for (int n = 0; n < 4; ++n) {
      const int gcol = rowB0 + wc * 64 + n * 16 + frow;
#pragma unroll
      for (int i = 0; i < 4; ++i) {
        const size_t grow = grow0 + i;
        float v = acc[m][n][i];
        if (MODE == 0) {
          v += bias[gcol];
          if (gcol < 768)
            ((__hip_bfloat16*)out0)[grow * 768 + gcol] = __float2bfloat16(v);
          else
            ((__hip_bfloat16*)out1)[grow * 768 + gcol - 768] = __float2bfloat16(v);
        } else if (MODE == 1) {
          if (gcol < 768) {
            v += bias[gcol];
            float sp = (v > 20.f) ? v : log1pf(expf(v));
            ((__hip_bfloat16*)out0)[grow * 768 + gcol] = __float2bfloat16(sp);
          } else if (gcol < 784) {
            ((float*)out1)[grow * 16 + (gcol - 768)] = v;
          } else if (gcol < 800) {
            ((float*)out2)[grow * 16 + (gcol - 784)] = v;
          }
        } else {
          ((float*)out0)[grow * 768 + gcol] = v + bias[gcol];
        }
      }
    }
  }
#undef STAGE
#undef VMW
#undef BAR
}

// ---------------------------------------------------------------------------
// ABLATION PROBE 1: ds_read + MFMA + barrier loop (production addressing,
// production barrier structure), staging done ONCE up front -> no VMEM in
// the loop.  4x outer repeat (expected duration identifies the wall).
// ---------------------------------------------------------------------------
__global__ __launch_bounds__(256, 3) void probe_mfma_lds(
    const __hip_bfloat16* __restrict__ Amat, const __hip_bfloat16* __restrict__ Bw,
    float* __restrict__ dump, const int gxn) {
  constexpr int K  = 768;
  constexpr int KT = 24;
  __shared__ char lds[49152];
  const int tid  = threadIdx.x;
  const int lane = tid & 63, wave = tid >> 6;
  const int wr = wave >> 1, wc = wave & 1;

  const int nwg = gridDim.x, id = blockIdx.x;
  const int swz = (id & 7) * (nwg >> 3) + (id >> 3);
  const int tm = swz / gxn, tn = swz - tm * gxn;
  const int rowA0 = tm * 128, rowB0 = tn * 128;

  const int srow = tid >> 2;
  const int scol = (((tid & 3) ^ ((srow >> 1) & 3)) << 3);
  const __hip_bfloat16* gA = Amat + (size_t)(rowA0 + srow) * K + scol;
  const __hip_bfloat16* gB = Bw   + (size_t)(rowB0 + srow) * K + scol;
  const int ldst = tid << 4;

  const int frow = lane & 15, fq = lane >> 4;
  const int pc = (fq << 4) ^ (((frow >> 1) & 3) << 4);
  const int aoff = ((wr * 64 + frow) << 6) + pc;
  const int boff = ((wc * 64 + frow) << 6) + pc;

  f32x4 acc[4][4];
#pragma unroll
  for (int m = 0; m < 4; ++m)
#pragma unroll
    for (int n = 0; n < 4; ++n) acc[m][n] = (f32x4){0.f, 0.f, 0.f, 0.f};

  // stage 3 buffers once
#pragma unroll
  for (int t = 0; t < 3; ++t) {
    const __hip_bfloat16* sA = gA + t * 32;
    const __hip_bfloat16* sB = gB + t * 32;
    char* dA = lds + t * 16384 + ldst;
    char* dB = dA + 8192;
    gload_lds16(sA, dA);
    gload_lds16(sA + (size_t)64 * K, dA + 4096);
    gload_lds16(sB, dB);
    gload_lds16(sB + (size_t)64 * K, dB + 4096);
  }
  asm volatile("s_waitcnt vmcnt(0)" ::: "memory");
  __builtin_amdgcn_s_barrier();

  for (int r = 0; r < 4; ++r) {
    int bc = 0;
    for (int kt = 0; kt < KT; ++kt) {
      short8 a[4], b[4];
      const char* ba = lds + bc * 16384;
#pragma unroll
      for (int m = 0; m < 4; ++m) a[m] = *(const short8*)(ba + aoff + m * 1024);
#pragma unroll
      for (int n = 0; n < 4; ++n) b[n] = *(const short8*)(ba + 8192 + boff + n * 1024);
      __builtin_amdgcn_s_setprio(1);
#pragma unroll
      for (int m = 0; m < 4; ++m)
#pragma unroll
        for (int n = 0; n < 4; ++n)
          acc[m][n] = __builtin_amdgcn_mfma_f32_16x16x32_bf16(a[m], b[n], acc[m][n], 0, 0, 0);
      __builtin_amdgcn_s_setprio(0);
      __builtin_amdgcn_s_barrier();
      bc = bc + 1 >= 3 ? 0 : bc + 1;
    }
  }
  // keep everything live
  float s = 0.f;
#pragma unroll
  for (int m = 0; m < 4; ++m)
#pragma unroll
    for (int n = 0; n < 4; ++n)
#pragma unroll
      for (int i = 0; i < 4; ++i) s += acc[m][n][i];
  dump[blockIdx.x * 256 + tid] = s;
}

// ---------------------------------------------------------------------------
// ABLATION PROBE 2: gload_lds staging + vmcnt(4) + barrier skeleton
// (production pacing), NO ds_read / MFMA.  4x outer repeat.
// ---------------------------------------------------------------------------
__global__ __launch_bounds__(256, 3) void probe_stage_vm(
    const __hip_bfloat16* __restrict__ Amat, const __hip_bfloat16* __restrict__ Bw,
    float* __restrict__ dump, const int gxn) {
  constexpr int K  = 768;
  constexpr int KT = 24;
  __shared__ char lds[49152];
  const int tid  = threadIdx.x;

  const int nwg = gridDim.x, id = blockIdx.x;
  const int swz = (id & 7) * (nwg >> 3) + (id >> 3);
  const int tm = swz / gxn, tn = swz - tm * gxn;
  const int rowA0 = tm * 128, rowB0 = tn * 128;

  const int srow = tid >> 2;
  const int scol = (((tid & 3) ^ ((srow >> 1) & 3)) << 3);
  const __hip_bfloat16* gA = Amat + (size_t)(rowA0 + srow) * K + scol;
  const __hip_bfloat16* gB = Bw   + (size_t)(rowB0 + srow) * K + scol;
  const int ldst = tid << 4;

#define PSTAGE(buf, kt)                                                         \
  {                                                                             \
    const __hip_bfloat16* sA = gA + (kt) * 32;                                  \
    const __hip_bfloat16* sB = gB + (kt) * 32;                                  \
    char* dA = lds + (buf) * 16384 + ldst;                                      \
    char* dB = dA + 8192;                                                       \
    gload_lds16(sA, dA);                                                        \
    gload_lds16(sA + (size_t)64 * K, dA + 4096);                                \
    gload_lds16(sB, dB);                                                        \
    gload_lds16(sB + (size_t)64 * K, dB + 4096);                                \
  }

  for (int r = 0; r < 4; ++r) {
    PSTAGE(0, 0);
    PSTAGE(1, 1);
    asm volatile("s_waitcnt vmcnt(4)" ::: "memory");
    __builtin_amdgcn_s_barrier();
    int bc = 0;
    for (int kt = 0; kt < KT; ++kt) {
      const bool st = (kt + 2 < KT);
      if (st) {
        const int b2 = bc + 2 >= 3 ? bc - 1 : bc + 2;
        PSTAGE(b2, kt + 2);
      }
      if (st)                asm volatile("s_waitcnt vmcnt(4)" ::: "memory");
      else if (kt + 2 == KT) asm volatile("s_waitcnt vmcnt(0)" ::: "memory");
      __builtin_amdgcn_s_barrier();
      bc = bc + 1 >= 3 ? 0 : bc + 1;
    }
  }
#undef PSTAGE
  // keep LDS writes observable
  dump[blockIdx.x * 256 + tid] = *(const float*)(lds + (tid << 4));
}

// ---------------------------------------------------------------------------
// Depthwise conv1d (K=3, pad=1) + bias + SiLU, short8-vectorized.
// ---------------------------------------------------------------------------
__global__ __launch_bounds__(256) void conv_silu8(
    const __hip_bfloat16* __restrict__ xin, const float* __restrict__ conv_w,
    const float* __restrict__ conv_b, __hip_bfloat16* __restrict__ xc) {
  const int idx = blockIdx.x * 256 + threadIdx.x;   // over BLD/8
  const int d8 = (idx % 96) * 8;
  const int t  = (idx / 96) % SEQL;
  const size_t base = (size_t)idx * 8;

  short8 x0 = *(const short8*)(xin + base);
  short8 xm = {}, xp = {};
  if (t > 0)        xm = *(const short8*)(xin + base - 768);
  if (t < SEQL - 1) xp = *(const short8*)(xin + base + 768);

  const float4* cw4 = (const float4*)(conv_w + d8 * 3);  // 24 floats
  float4 cw[6];
#pragma unroll
  for (int q = 0; q < 6; ++q) cw[q] = cw4[q];
  float4 cb0 = *(const float4*)(conv_b + d8);
  float4 cb1 = *(const float4*)(conv_b + d8 + 4);
  const float* cwf = (const float*)cw;
  const float* cbf0 = (const float*)&cb0;
  const float* cbf1 = (const float*)&cb1;

  short8 r;
#pragma unroll
  for (int e = 0; e < 8; ++e) {
    float acc = (e < 4) ? cbf0[e] : cbf1[e - 4];
    acc = fmaf(cwf[e * 3 + 0], b2f(xm[e]), acc);
    acc = fmaf(cwf[e * 3 + 1], b2f(x0[e]), acc);
    acc = fmaf(cwf[e * 3 + 2], b2f(xp[e]), acc);
    const float sig = 1.f / (1.f + __expf(-acc));
    r[e] = f2b(acc * sig);
  }
  *(short8*)(xc + base) = r;
}

// ---------------------------------------------------------------------------
// Scan pass 1: per (b, d, chunk) local scan with h_in = 0
// ---------------------------------------------------------------------------
__global__ __launch_bounds__(256) void scan_pass1(
    const __hip_bfloat16* __restrict__ delta, const __hip_bfloat16* __restrict__ xconv,
    const float* __restrict__ Bsel, const float* __restrict__ A2,
    float* __restrict__ sumdt, float* __restrict__ Sbuf) {
  const int d = blockIdx.x * 256 + threadIdx.x;
  const int b = blockIdx.y, c = blockIdx.z;
  __shared__ float sB[TCHUNK * 16];
  ((float4*)sB)[threadIdx.x] =
      ((const float4*)(Bsel + ((size_t)b * SEQL + c * TCHUNK) * 16))[threadIdx.x];
  __syncthreads();

  float a2[16];
#pragma unroll
  for (int n = 0; n < 16; ++n) a2[n] = A2[d * 16 + n];
  float h[16] = {};
  float sdt = 0.f;
  const size_t base = ((size_t)b * SEQL + c * TCHUNK) * 768 + d;
  for (int t = 0; t < TCHUNK; ++t) {
    const float dt = b2f(((const short*)delta)[base + (size_t)t * 768]);
    const float x = b2f(((const short*)xconv)[base + (size_t)t * 768]);
    sdt += dt;
    const float dtx = dt * x;
    const float* Br = &sB[t * 16];
#pragma unroll
    for (int n = 0; n < 16; ++n) {
      const float a = exp2f(dt * a2[n]);
      h[n] = fmaf(a, h[n], dtx * Br[n]);
    }
  }
  sumdt[((size_t)b * NCHUNK + c) * 768 + d] = sdt;
#pragma unroll
  for (int n = 0; n < 16; ++n)
    Sbuf[(((size_t)b * NCHUNK + c) * 16 + n) * 768 + d] = h[n];
}

// ---------------------------------------------------------------------------
// Scan pass 2: serial carry over chunks, one thread per (b, n, d) chain.
// ---------------------------------------------------------------------------
__global__ __launch_bounds__(256) void scan_carry(
    const float* __restrict__ sumdt, const float* __restrict__ Sbuf,
    const float* __restrict__ A2, float* __restrict__ Hin) {
  const int idx = blockIdx.x * 256 + threadIdx.x;  // 0..98303
  const int d = idx % 768;
  const int n = (idx / 768) & 15;
  const int b = idx / (768 * 16);
  const float a2 = A2[d * 16 + n];
  float h = 0.f;
  for (int c = 0; c < NCHUNK; ++c) {
    const size_t hb = (((size_t)(b * NCHUNK + c)) * 16 + n) * 768 + d;
    Hin[hb] = h;
    const float sd = sumdt[(b * NCHUNK + c) * 768 + d];
    h = fmaf(exp2f(sd * a2), h, Sbuf[hb]);
  }
}

// ---------------------------------------------------------------------------
// Scan pass 3: replay with correct h_in; fuse D-skip + silu(z) gating -> bf16
// ---------------------------------------------------------------------------
__global__ __launch_bounds__(256) void scan_pass3(
    const __hip_bfloat16* __restrict__ delta, const __hip_bfloat16* __restrict__ xconv,
    const __hip_bfloat16* __restrict__ zb, const float* __restrict__ Bsel,
    const float* __restrict__ Csel, const float* __restrict__ A2,
    const float* __restrict__ Hin, const float* __restrict__ Dp,
    __hip_bfloat16* __restrict__ yg) {
  const int d = blockIdx.x * 256 + threadIdx.x;
  const int b = blockIdx.y, c = blockIdx.z;
  __shared__ float sB[TCHUNK * 16], sC[TCHUNK * 16];
  {
    const size_t off = ((size_t)b * SEQL + c * TCHUNK) * 16;
    ((float4*)sB)[threadIdx.x] = ((const float4*)(Bsel + off))[threadIdx.x];
    ((float4*)sC)[threadIdx.x] = ((const float4*)(Csel + off))[threadIdx.x];
  }
  __syncthreads();

  float a2[16];
#pragma unroll
  for (int n = 0; n < 16; ++n) a2[n] = A2[d * 16 + n];
  float h[16];
  {
    const size_t hb = ((size_t)b * NCHUNK + c) * 16 * 768 + d;
#pragma unroll
    for (int n = 0; n < 16; ++n) h[n] = Hin[hb + (size_t)n * 768];
  }
  const float Dpd = Dp[d];
  const size_t base = ((size_t)b * SEQL + c * TCHUNK) * 768 + d;
  for (int t = 0; t < TCHUNK; ++t) {
    const float dt = b2f(((const short*)delta)[base + (size_t)t * 768]);
    const float x = b2f(((const short*)xconv)[base + (size_t)t * 768]);
    const float dtx = dt * x;
    const float* Br = &sB[t * 16];
    const float* Cr = &sC[t * 16];
    float y = 0.f;
#pragma unroll
    for (int n = 0; n < 16; ++n) {
      const float a = exp2f(dt * a2[n]);
      h[n] = fmaf(a, h[n], dtx * Br[n]);
      y = fmaf(h[n], Cr[n], y);
    }
    const float z = b2f(((const short*)zb)[base + (size_t)t * 768]);
    const float sig = 1.f / (1.f + __expf(-z));
    const float out = (y + x * Dpd) * (z * sig);
    yg[base + (size_t)t * 768] = __float2bfloat16(out);
  }
}

// ---------------------------------------------------------------------------
// Launch
// ---------------------------------------------------------------------------
extern "C" void kernel_launch(void* const* d_in, const int* in_sizes, int n_in,
                              void* d_out, int out_size, void* d_ws, size_t ws_size,
                              hipStream_t stream) {
  const float* x       = (const float*)d_in[0];
  const float* A_log   = (const float*)d_in[1];
  const float* D_param = (const float*)d_in[2];
  const float* B_proj  = (const float*)d_in[3];
  const float* C_proj  = (const float*)d_in[4];
  const float* delta_w = (const float*)d_in[5];
  const float* delta_b = (const float*)d_in[6];
  const float* in_w    = (const float*)d_in[7];
  const float* in_b    = (const float*)d_in[8];
  const float* out_w   = (const float*)d_in[9];
  const float* out_b   = (const float*)d_in[10];
  const float* conv_w  = (const float*)d_in[11];
  const float* conv_b  = (const float*)d_in[12];

  char* ws = (char*)d_ws;
  __hip_bfloat16* xb       = (__hip_bfloat16*)(ws + 0);          // reused as yg later
  __hip_bfloat16* w_in_b   = (__hip_bfloat16*)(ws + 25165824);
  __hip_bfloat16* w_dbc_b  = (__hip_bfloat16*)(ws + 27525120);   // 896 x 768
  __hip_bfloat16* w_out_b  = (__hip_bfloat16*)(ws + 28901376);
  float*          A2       = (float*)(ws + 30081024);
  __hip_bfloat16* xin_b    = (__hip_bfloat16*)(ws + 30130176);
  __hip_bfloat16* z_b      = (__hip_bfloat16*)(ws + 55296000);
  __hip_bfloat16* xconv_b  = (__hip_bfloat16*)(ws + 80461824);
  __hip_bfloat16* delta_bf = (__hip_bfloat16*)(ws + 105627648);
  float*          Bsel     = (float*)(ws + 130793472);
  float*          Csel     = (float*)(ws + 131842048);
  float*          sumdt    = (float*)(ws + 132890624);
  float*          Sbuf     = (float*)(ws + 133677056);
  float*          Hin      = (float*)(ws + 146259968);
  float*          pdump    = (float*)(ws + 168000000);           // probe scratch
  __hip_bfloat16* yg       = xb;  // x (bf16) dead after in_proj GEMM

  const int BLD = BATCH * SEQL * D_MODEL;  // 12,582,912

  // 1. prep: x->bf16, weights->bf16, A2
  prep_all<<<21936, 256, 0, stream>>>(x, in_w, delta_w, B_proj, C_proj, out_w, A_log,
                                      xb, w_in_b, w_dbc_b, w_out_b, A2);
  // 2. in_proj GEMM [16384,1536] : 128 x 12 tiles = 1536 blocks
  gemm128tb<0><<<1536, 256, 0, stream>>>(xb, w_in_b, in_b, xin_b, z_b, nullptr, 12);
  // 3. depthwise conv + silu (short8)
  conv_silu8<<<BLD / 8 / 256, 256, 0, stream>>>(xin_b, conv_w, conv_b, xconv_b);
  // 4. delta/B/C GEMM [16384,896] : 128 x 7 tiles = 896 blocks
  gemm128tb<1><<<896, 256, 0, stream>>>(xconv_b, w_dbc_b, delta_b, delta_bf, Bsel, Csel, 7);
  // 5-7. chunked scan
  scan_pass1<<<dim3(3, BATCH, NCHUNK), 256, 0, stream>>>(delta_bf, xconv_b, Bsel, A2, sumdt, Sbuf);
  scan_carry<<<384, 256, 0, stream>>>(sumdt, Sbuf, A2, Hin);
  scan_pass3<<<dim3(3, BATCH, NCHUNK), 256, 0, stream>>>(delta_bf, xconv_b, z_b, Bsel, Csel, A2,
                                                         Hin, D_param, yg);
  // 8. out_proj GEMM [16384,768] : 128 x 6 tiles = 768 blocks
  gemm128tb<2><<<768, 256, 0, stream>>>(yg, w_out_b, out_b, (float*)d_out, nullptr, nullptr, 6);

  // --- ablation probes (one-time information spend; do not affect d_out) ---
  probe_mfma_lds<<<1536, 256, 0, stream>>>(xb, w_in_b, pdump, 12);
  probe_stage_vm<<<1536, 256, 0, stream>>>(xb, w_in_b, pdump + 1536 * 256, 12);
}

// Round 9
// 355.575 us; speedup vs baseline: 1.7778x; 1.7778x over previous
//
#include <hip/hip_runtime.h>
#include <hip/hip_bf16.h>

// Problem constants
#define D_MODEL 768
#define SEQL    2048
#define BATCH   8
#define NSTATE  16
#define NCHUNK  32
#define TCHUNK  64   // SEQL / NCHUNK

typedef __attribute__((ext_vector_type(8))) short short8;
typedef __attribute__((ext_vector_type(4))) float f32x4;

typedef const __attribute__((address_space(1))) unsigned int gas1_t;
typedef __attribute__((address_space(3))) unsigned int las3_t;

__device__ __forceinline__ void gload_lds16(const void* g, void* l) {
  __builtin_amdgcn_global_load_lds((gas1_t*)g, (las3_t*)l, 16, 0, 0);
}

__device__ __forceinline__ float b2f(short s) {
  return __uint_as_float(((unsigned)(unsigned short)s) << 16);
}
__device__ __forceinline__ short f2b(float f) {
  __hip_bfloat16 h = __float2bfloat16(f);
  return *reinterpret_cast<short*>(&h);
}

// ---------------------------------------------------------------------------
// Tiled bf16 layout (K=768): [rtile 128][ktile 32] tiles of 8KB whose byte
// image equals the GEMM's swizzled LDS image:
//   byte = tile*8192 + (r&127)*64 + (((k>>3) ^ ((r>>1)&3)) & 3)*16 + (k&7)*2
// Staging a K-tile is then ONE contiguous 8KB read (8 lines/KB, sequential)
// instead of 16-line-divergent gathers (the 49 cyc/instr wall R7 isolated).
// ---------------------------------------------------------------------------
__device__ __forceinline__ unsigned tix(int r, int k) {
  return (unsigned)((((r >> 7) * 24 + (k >> 5)) << 13) + ((r & 127) << 6) +
                    ((((k >> 3) ^ ((r >> 1) & 3)) & 3) << 4) + ((k & 7) << 1));
}

// pack 8 f32 -> short8 bf16
__device__ __forceinline__ short8 pack8(const float* v) {
  short8 o;
#pragma unroll
  for (int e = 0; e < 8; ++e) o[e] = f2b(v[e]);
  return o;
}

// ---------------------------------------------------------------------------
// Merged prep: x -> xb (tiled bf16), weights -> tiled bf16, A2 table.
// counts: x 16384*96 + in_w 1536*96 + dbc 896*96 + out_w 768*96 + A2 12288
//       = 1,892,352 = 7392 * 256
// ---------------------------------------------------------------------------
__global__ __launch_bounds__(256) void prep_all(
    const float* __restrict__ x, const float* __restrict__ in_w,
    const float* __restrict__ delta_w, const float* __restrict__ Bp,
    const float* __restrict__ Cp, const float* __restrict__ out_w,
    const float* __restrict__ A_log,
    char* __restrict__ xb, char* __restrict__ w_in,
    char* __restrict__ w_dbc, char* __restrict__ w_out,
    float* __restrict__ A2) {
  int i = blockIdx.x * 256 + threadIdx.x;
  if (i < 16384 * 96) {
    const int r = i / 96, k8 = i - r * 96;
    float v[8];
    *(float4*)(v) = *(const float4*)(x + (size_t)r * 768 + k8 * 8);
    *(float4*)(v + 4) = *(const float4*)(x + (size_t)r * 768 + k8 * 8 + 4);
    *(short8*)(xb + tix(r, k8 * 8)) = pack8(v);
    return;
  }
  i -= 16384 * 96;
  if (i < 1536 * 96) {
    const int r = i / 96, k8 = i - r * 96;
    float v[8];
    *(float4*)(v) = *(const float4*)(in_w + (size_t)r * 768 + k8 * 8);
    *(float4*)(v + 4) = *(const float4*)(in_w + (size_t)r * 768 + k8 * 8 + 4);
    *(short8*)(w_in + tix(r, k8 * 8)) = pack8(v);
    return;
  }
  i -= 1536 * 96;
  if (i < 896 * 96) {   // rows: 768 delta, 16 B, 16 C, 96 zero-pad
    const int r = i / 96, k8 = i - r * 96;
    float v[8];
    const float* src = (r < 768)   ? delta_w + (size_t)r * 768
                       : (r < 784) ? Bp + (size_t)(r - 768) * 768
                       : (r < 800) ? Cp + (size_t)(r - 784) * 768
                                   : nullptr;
    if (src) {
      *(float4*)(v) = *(const float4*)(src + k8 * 8);
      *(float4*)(v + 4) = *(const float4*)(src + k8 * 8 + 4);
    } else {
#pragma unroll
      for (int e = 0; e < 8; ++e) v[e] = 0.f;
    }
    *(short8*)(w_dbc + tix(r, k8 * 8)) = pack8(v);
    return;
  }
  i -= 896 * 96;
  if (i < 768 * 96) {
    const int r = i / 96, k8 = i - r * 96;
    float v[8];
    *(float4*)(v) = *(const float4*)(out_w + (size_t)r * 768 + k8 * 8);
    *(float4*)(v + 4) = *(const float4*)(out_w + (size_t)r * 768 + k8 * 8 + 4);
    *(short8*)(w_out + tix(r, k8 * 8)) = pack8(v);
    return;
  }
  i -= 768 * 96;
  A2[i] = -expf(A_log[i]) * 1.44269504088896f;  // A * log2(e)
}

// ---------------------------------------------------------------------------
// Production GEMM: 128x128 tile, BK=32, 4 waves, 3 bufs x 16KB = 48KB LDS
// -> 3 blocks/CU.  Counted vmcnt(4).  A and B pre-tiled (tix layout), so
// STAGE = contiguous 8KB per operand.  ds_read offsets identical to R6
// (0 bank conflicts measured).
// MODE 0: in_proj -> tiled-bf16 x_in / tiled-bf16 z, +bias
// MODE 1: dbc     -> tiled-bf16 softplus(delta+bias), f32 B, f32 C
// MODE 2: out_proj-> linear f32 out + bias (d_out)
// ---------------------------------------------------------------------------
template <int MODE>
__global__ __launch_bounds__(256, 3) void gemm128tb(
    const char* __restrict__ Amat, const char* __restrict__ Bw,
    const float* __restrict__ bias, void* __restrict__ out0,
    void* __restrict__ out1, void* __restrict__ out2, const int gxn) {
  constexpr int KT = 24;           // 768 / 32
  __shared__ char lds[49152];      // 3 x 16KB
  const int tid  = threadIdx.x;
  const int lane = tid & 63, wave = tid >> 6;
  const int wr = wave >> 1, wc = wave & 1;

  const int nwg = gridDim.x, id = blockIdx.x;
  const int swz = (id & 7) * (nwg >> 3) + (id >> 3);
  const int tm = swz / gxn, tn = swz - tm * gxn;

  // tiled staging bases (contiguous: tid*16)
  const char* gA = Amat + ((size_t)tm * KT) * 8192 + (tid << 4);
  const char* gB = Bw   + ((size_t)tn * KT) * 8192 + (tid << 4);
  const int ldst = tid << 4;

  // fragment ds_read offsets (swizzled; matches tix image)
  const int frow = lane & 15, fq = lane >> 4;
  const int pc = (fq << 4) ^ (((frow >> 1) & 3) << 4);
  const int aoff = ((wr * 64 + frow) << 6) + pc;
  const int boff = ((wc * 64 + frow) << 6) + pc;

  f32x4 acc[4][4];
#pragma unroll
  for (int m = 0; m < 4; ++m)
#pragma unroll
    for (int n = 0; n < 4; ++n) acc[m][n] = (f32x4){0.f, 0.f, 0.f, 0.f};

#define STAGE(buf, kt)                                                          \
  {                                                                             \
    const char* sA = gA + (kt) * 8192;                                          \
    const char* sB = gB + (kt) * 8192;                                          \
    char* dA = lds + (buf) * 16384 + ldst;                                      \
    char* dB = dA + 8192;                                                       \
    gload_lds16(sA, dA);                                                        \
    gload_lds16(sA + 4096, dA + 4096);                                          \
    gload_lds16(sB, dB);                                                        \
    gload_lds16(sB + 4096, dB + 4096);                                          \
  }
#define VMW(n) asm volatile("s_waitcnt vmcnt(" #n ")" ::: "memory")
#define BAR    __builtin_amdgcn_s_barrier()

  STAGE(0, 0);
  STAGE(1, 1);
  VMW(4);
  BAR;

  int bc = 0;  // current buffer = kt % 3
  for (int kt = 0; kt < KT; ++kt) {
    short8 a[4], b[4];
    const char* ba = lds + bc * 16384;
#pragma unroll
    for (int m = 0; m < 4; ++m) a[m] = *(const short8*)(ba + aoff + m * 1024);
#pragma unroll
    for (int n = 0; n < 4; ++n) b[n] = *(const short8*)(ba + 8192 + boff + n * 1024);
    const bool st = (kt + 2 < KT);
    if (st) {
      const int b2 = bc + 2 >= 3 ? bc - 1 : bc + 2;
      STAGE(b2, kt + 2);
    }
    __builtin_amdgcn_s_setprio(1);
#pragma unroll
    for (int m = 0; m < 4; ++m)
#pragma unroll
      for (int n = 0; n < 4; ++n)
        acc[m][n] = __builtin_amdgcn_mfma_f32_16x16x32_bf16(a[m], b[n], acc[m][n], 0, 0, 0);
    __builtin_amdgcn_s_setprio(0);
    if (st)                VMW(4);
    else if (kt + 2 == KT) VMW(0);
    BAR;
    bc = bc + 1 >= 3 ? 0 : bc + 1;
  }

  // epilogue (C/D layout: col = lane&15, row = (lane>>4)*4 + i)
  const int rowA0 = tm * 128, rowB0 = tn * 128;
#pragma unroll
  for (int m = 0; m < 4; ++m) {
    const int grow0 = rowA0 + wr * 64 + m * 16 + fq * 4;
#pragma unroll
    for (int n = 0; n < 4; ++n) {
      const int gcol = rowB0 + wc * 64 + n * 16 + frow;
#pragma unroll
      for (int i = 0; i < 4; ++i) {
        const int grow = grow0 + i;
        float v = acc[m][n][i];
        if (MODE == 0) {
          v += bias[gcol];
          if (gcol < 768)
            *(short*)((char*)out0 + tix(grow, gcol)) = f2b(v);
          else
            *(short*)((char*)out1 + tix(grow, gcol - 768)) = f2b(v);
        } else if (MODE == 1) {
          if (gcol < 768) {
            v += bias[gcol];
            float sp = (v > 20.f) ? v : log1pf(expf(v));
            *(short*)((char*)out0 + tix(grow, gcol)) = f2b(sp);
          } else if (gcol < 784) {
            ((float*)out1)[(size_t)grow * 16 + (gcol - 768)] = v;
          } else if (gcol < 800) {
            ((float*)out2)[(size_t)grow * 16 + (gcol - 784)] = v;
          }
        } else {
          ((float*)out0)[(size_t)grow * 768 + gcol] = v + bias[gcol];
        }
      }
    }
  }
#undef STAGE
#undef VMW
#undef BAR
}

// ---------------------------------------------------------------------------
// Depthwise conv1d (K=3, pad=1) + bias + SiLU, tiled in/out, short8 slots.
// ---------------------------------------------------------------------------
__global__ __launch_bounds__(256) void conv_silu8(
    const char* __restrict__ xin, const float* __restrict__ conv_w,
    const float* __restrict__ conv_b, char* __restrict__ xc) {
  const int idx = blockIdx.x * 256 + threadIdx.x;   // over 16384*96
  const int r  = idx / 96;
  const int d8 = (idx - r * 96) * 8;
  const int t  = r & (SEQL - 1);

  short8 x0 = *(const short8*)(xin + tix(r, d8));
  short8 xm = {}, xp = {};
  if (t > 0)        xm = *(const short8*)(xin + tix(r - 1, d8));
  if (t < SEQL - 1) xp = *(const short8*)(xin + tix(r + 1, d8));

  const float4* cw4 = (const float4*)(conv_w + d8 * 3);  // 24 floats
  float4 cw[6];
#pragma unroll
  for (int q = 0; q < 6; ++q) cw[q] = cw4[q];
  float4 cb0 = *(const float4*)(conv_b + d8);
  float4 cb1 = *(const float4*)(conv_b + d8 + 4);
  const float* cwf = (const float*)cw;
  const float* cbf0 = (const float*)&cb0;
  const float* cbf1 = (const float*)&cb1;

  short8 res;
#pragma unroll
  for (int e = 0; e < 8; ++e) {
    float acc = (e < 4) ? cbf0[e] : cbf1[e - 4];
    acc = fmaf(cwf[e * 3 + 0], b2f(xm[e]), acc);
    acc = fmaf(cwf[e * 3 + 1], b2f(x0[e]), acc);
    acc = fmaf(cwf[e * 3 + 2], b2f(xp[e]), acc);
    const float sig = 1.f / (1.f + __expf(-acc));
    res[e] = f2b(acc * sig);
  }
  *(short8*)(xc + tix(r, d8)) = res;
}

// ---------------------------------------------------------------------------
// Scan pass 1: per (b, d, chunk) local scan with h_in = 0.
// Tiled address: tb = tile-base + row-base ONLY (slot and k-low added per t).
// r0 is 64-aligned => (r0>>1)&3 == 0 and row bits 1..2 == t bits 1..2, so
// slot(t) = (sd0 ^ (t>>1)) & 3.  (R8 bug: base kept klo and re-added it.)
// ---------------------------------------------------------------------------
__global__ __launch_bounds__(256) void scan_pass1(
    const char* __restrict__ delta, const char* __restrict__ xconv,
    const float* __restrict__ Bsel, const float* __restrict__ A2,
    float* __restrict__ sumdt, float* __restrict__ Sbuf) {
  const int d = blockIdx.x * 256 + threadIdx.x;
  const int b = blockIdx.y, c = blockIdx.z;
  __shared__ float sB[TCHUNK * 16];
  ((float4*)sB)[threadIdx.x] =
      ((const float4*)(Bsel + ((size_t)b * SEQL + c * TCHUNK) * 16))[threadIdx.x];
  __syncthreads();

  float a2[16];
#pragma unroll
  for (int n = 0; n < 16; ++n) a2[n] = A2[d * 16 + n];
  float h[16] = {};
  float sdt = 0.f;
  const int r0 = b * SEQL + c * TCHUNK;       // 64-aligned
  const unsigned tb = (((unsigned)((r0 >> 7) * 24 + (d >> 5))) << 13) + ((r0 & 127) << 6);
  const unsigned sd0 = (d >> 3) & 3;
  const unsigned klo = (d & 7) << 1;
  for (int t = 0; t < TCHUNK; ++t) {
    const unsigned ro = tb + t * 64 + (((sd0 ^ ((unsigned)t >> 1)) & 3) << 4) + klo;
    const float dt = b2f(*(const short*)(delta + ro));
    const float x = b2f(*(const short*)(xconv + ro));
    sdt += dt;
    const float dtx = dt * x;
    const float* Br = &sB[t * 16];
#pragma unroll
    for (int n = 0; n < 16; ++n) {
      const float a = exp2f(dt * a2[n]);
      h[n] = fmaf(a, h[n], dtx * Br[n]);
    }
  }
  sumdt[((size_t)b * NCHUNK + c) * 768 + d] = sdt;
#pragma unroll
  for (int n = 0; n < 16; ++n)
    Sbuf[(((size_t)b * NCHUNK + c) * 16 + n) * 768 + d] = h[n];
}

// ---------------------------------------------------------------------------
// Scan pass 2: serial carry over chunks, one thread per (b, n, d) chain.
// ---------------------------------------------------------------------------
__global__ __launch_bounds__(256) void scan_carry(
    const float* __restrict__ sumdt, const float* __restrict__ Sbuf,
    const float* __restrict__ A2, float* __restrict__ Hin) {
  const int idx = blockIdx.x * 256 + threadIdx.x;  // 0..98303
  const int d = idx % 768;
  const int n = (idx / 768) & 15;
  const int b = idx / (768 * 16);
  const float a2 = A2[d * 16 + n];
  float h = 0.f;
  for (int c = 0; c < NCHUNK; ++c) {
    const size_t hb = (((size_t)(b * NCHUNK + c)) * 16 + n) * 768 + d;
    Hin[hb] = h;
    const float sd = sumdt[(b * NCHUNK + c) * 768 + d];
    h = fmaf(exp2f(sd * a2), h, Sbuf[hb]);
  }
}

// ---------------------------------------------------------------------------
// Scan pass 3: replay with correct h_in; fuse D-skip + silu(z) gating.
// Same fixed address decomposition as pass 1.
// ---------------------------------------------------------------------------
__global__ __launch_bounds__(256) void scan_pass3(
    const char* __restrict__ delta, const char* __restrict__ xconv,
    const char* __restrict__ zb, const float* __restrict__ Bsel,
    const float* __restrict__ Csel, const float* __restrict__ A2,
    const float* __restrict__ Hin, const float* __restrict__ Dp,
    char* __restrict__ yg) {
  const int d = blockIdx.x * 256 + threadIdx.x;
  const int b = blockIdx.y, c = blockIdx.z;
  __shared__ float sB[TCHUNK * 16], sC[TCHUNK * 16];
  {
    const size_t off = ((size_t)b * SEQL + c * TCHUNK) * 16;
    ((float4*)sB)[threadIdx.x] = ((const float4*)(Bsel + off))[threadIdx.x];
    ((float4*)sC)[threadIdx.x] = ((const float4*)(Csel + off))[threadIdx.x];
  }
  __syncthreads();

  float a2[16];
#pragma unroll
  for (int n = 0; n < 16; ++n) a2[n] = A2[d * 16 + n];
  float h[16];
  {
    const size_t hb = ((size_t)b * NCHUNK + c) * 16 * 768 + d;
#pragma unroll
    for (int n = 0; n < 16; ++n) h[n] = Hin[hb + (size_t)n * 768];
  }
  const float Dpd = Dp[d];
  const int r0 = b * SEQL + c * TCHUNK;
  const unsigned tb = (((unsigned)((r0 >> 7) * 24 + (d >> 5))) << 13) + ((r0 & 127) << 6);
  const unsigned sd0 = (d >> 3) & 3;
  const unsigned klo = (d & 7) << 1;
  for (int t = 0; t < TCHUNK; ++t) {
    const unsigned ro = tb + t * 64 + (((sd0 ^ ((unsigned)t >> 1)) & 3) << 4) + klo;
    const float dt = b2f(*(const short*)(delta + ro));
    const float x = b2f(*(const short*)(xconv + ro));
    const float dtx = dt * x;
    const float* Br = &sB[t * 16];
    const float* Cr = &sC[t * 16];
    float y = 0.f;
#pragma unroll
    for (int n = 0; n < 16; ++n) {
      const float a = exp2f(dt * a2[n]);
      h[n] = fmaf(a, h[n], dtx * Br[n]);
      y = fmaf(h[n], Cr[n], y);
    }
    const float z = b2f(*(const short*)(zb + ro));
    const float sig = 1.f / (1.f + __expf(-z));
    const float out = (y + x * Dpd) * (z * sig);
    *(short*)(yg + ro) = f2b(out);
  }
}

// ---------------------------------------------------------------------------
// Launch
// ---------------------------------------------------------------------------
extern "C" void kernel_launch(void* const* d_in, const int* in_sizes, int n_in,
                              void* d_out, int out_size, void* d_ws, size_t ws_size,
                              hipStream_t stream) {
  const float* x       = (const float*)d_in[0];
  const float* A_log   = (const float*)d_in[1];
  const float* D_param = (const float*)d_in[2];
  const float* B_proj  = (const float*)d_in[3];
  const float* C_proj  = (const float*)d_in[4];
  const float* delta_w = (const float*)d_in[5];
  const float* delta_b = (const float*)d_in[6];
  const float* in_w    = (const float*)d_in[7];
  const float* in_b    = (const float*)d_in[8];
  const float* out_w   = (const float*)d_in[9];
  const float* out_b   = (const float*)d_in[10];
  const float* conv_w  = (const float*)d_in[11];
  const float* conv_b  = (const float*)d_in[12];

  char* ws = (char*)d_ws;
  char*  xb       = ws + 0;            // tiled bf16 [16384][768]; reused as yg
  char*  w_in_b   = ws + 25165824;     // tiled bf16 [1536][768]
  char*  w_dbc_b  = ws + 27525120;     // tiled bf16 [896][768]
  char*  w_out_b  = ws + 28901376;     // tiled bf16 [768][768]
  float* A2       = (float*)(ws + 30081024);
  char*  xin_b    = ws + 30130176;     // tiled bf16
  char*  z_b      = ws + 55296000;     // tiled bf16
  char*  xconv_b  = ws + 80461824;     // tiled bf16
  char*  delta_bf = ws + 105627648;    // tiled bf16
  float* Bsel     = (float*)(ws + 130793472);
  float* Csel     = (float*)(ws + 131842048);
  float* sumdt    = (float*)(ws + 132890624);
  float* Sbuf     = (float*)(ws + 133677056);
  float* Hin      = (float*)(ws + 146259968);
  char*  yg       = xb;  // x (bf16) dead after in_proj GEMM

  // 1. prep: x->tiled bf16, weights->tiled bf16, A2
  prep_all<<<7392, 256, 0, stream>>>(x, in_w, delta_w, B_proj, C_proj, out_w, A_log,
                                     xb, w_in_b, w_dbc_b, w_out_b, A2);
  // 2. in_proj GEMM [16384,1536] : 128 x 12 tiles = 1536 blocks
  gemm128tb<0><<<1536, 256, 0, stream>>>(xb, w_in_b, in_b, xin_b, z_b, nullptr, 12);
  // 3. depthwise conv + silu (tiled short8)
  conv_silu8<<<16384 * 96 / 256, 256, 0, stream>>>(xin_b, conv_w, conv_b, xconv_b);
  // 4. delta/B/C GEMM [16384,896] : 128 x 7 tiles = 896 blocks
  gemm128tb<1><<<896, 256, 0, stream>>>(xconv_b, w_dbc_b, delta_b, delta_bf, Bsel, Csel, 7);
  // 5-7. chunked scan
  scan_pass1<<<dim3(3, BATCH, NCHUNK), 256, 0, stream>>>(delta_bf, xconv_b, Bsel, A2, sumdt, Sbuf);
  scan_carry<<<384, 256, 0, stream>>>(sumdt, Sbuf, A2, Hin);
  scan_pass3<<<dim3(3, BATCH, NCHUNK), 256, 0, stream>>>(delta_bf, xconv_b, z_b, Bsel, Csel, A2,
                                                         Hin, D_param, yg);
  // 8. out_proj GEMM [16384,768] : 128 x 6 tiles = 768 blocks
  gemm128tb<2><<<768, 256, 0, stream>>>(yg, w_out_b, out_b, (float*)d_out, nullptr, nullptr, 6);
}

// Round 10
// 353.311 us; speedup vs baseline: 1.7892x; 1.0064x over previous
//
#include <hip/hip_runtime.h>
#include <hip/hip_bf16.h>

// Problem constants
#define D_MODEL 768
#define SEQL    2048
#define BATCH   8
#define NSTATE  16
#define NCHUNK  32
#define TCHUNK  64   // SEQL / NCHUNK

typedef __attribute__((ext_vector_type(8))) short short8;
typedef __attribute__((ext_vector_type(4))) float f32x4;

__device__ __forceinline__ float b2f(short s) {
  return __uint_as_float(((unsigned)(unsigned short)s) << 16);
}
__device__ __forceinline__ short f2b(float f) {
  __hip_bfloat16 h = __float2bfloat16(f);
  return *reinterpret_cast<short*>(&h);
}

// ---------------------------------------------------------------------------
// Tiled bf16 layout (K=768): [rtile 128][ktile 32] tiles of 8KB:
//   byte = tile*8192 + (r&127)*64 + (((k>>3) ^ ((r>>1)&3)) & 3)*16 + (k&7)*2
// A wave's 16x32 MFMA fragment (16 rows x 4 k-slots x 16B) is a CONTIGUOUS
// 1KB block in this layout -> fragments load straight from global through the
// L1/L2 vector path (global_load_dwordx4, perfectly coalesced), bypassing the
// ~13 TB/s global_load_lds wall that R7/R9 isolated (m97/m201 both sit on it).
// ---------------------------------------------------------------------------
__device__ __forceinline__ unsigned tix(int r, int k) {
  return (unsigned)((((r >> 7) * 24 + (k >> 5)) << 13) + ((r & 127) << 6) +
                    ((((k >> 3) ^ ((r >> 1) & 3)) & 3) << 4) + ((k & 7) << 1));
}

// pack 8 f32 -> short8 bf16
__device__ __forceinline__ short8 pack8(const float* v) {
  short8 o;
#pragma unroll
  for (int e = 0; e < 8; ++e) o[e] = f2b(v[e]);
  return o;
}

// ---------------------------------------------------------------------------
// Merged prep: x -> xb (tiled bf16), weights -> tiled bf16, A2 table.
// counts: x 16384*96 + in_w 1536*96 + dbc 896*96 + out_w 768*96 + A2 12288
//       = 1,892,352 = 7392 * 256
// ---------------------------------------------------------------------------
__global__ __launch_bounds__(256) void prep_all(
    const float* __restrict__ x, const float* __restrict__ in_w,
    const float* __restrict__ delta_w, const float* __restrict__ Bp,
    const float* __restrict__ Cp, const float* __restrict__ out_w,
    const float* __restrict__ A_log,
    char* __restrict__ xb, char* __restrict__ w_in,
    char* __restrict__ w_dbc, char* __restrict__ w_out,
    float* __restrict__ A2) {
  int i = blockIdx.x * 256 + threadIdx.x;
  if (i < 16384 * 96) {
    const int r = i / 96, k8 = i - r * 96;
    float v[8];
    *(float4*)(v) = *(const float4*)(x + (size_t)r * 768 + k8 * 8);
    *(float4*)(v + 4) = *(const float4*)(x + (size_t)r * 768 + k8 * 8 + 4);
    *(short8*)(xb + tix(r, k8 * 8)) = pack8(v);
    return;
  }
  i -= 16384 * 96;
  if (i < 1536 * 96) {
    const int r = i / 96, k8 = i - r * 96;
    float v[8];
    *(float4*)(v) = *(const float4*)(in_w + (size_t)r * 768 + k8 * 8);
    *(float4*)(v + 4) = *(const float4*)(in_w + (size_t)r * 768 + k8 * 8 + 4);
    *(short8*)(w_in + tix(r, k8 * 8)) = pack8(v);
    return;
  }
  i -= 1536 * 96;
  if (i < 896 * 96) {   // rows: 768 delta, 16 B, 16 C, 96 zero-pad
    const int r = i / 96, k8 = i - r * 96;
    float v[8];
    const float* src = (r < 768)   ? delta_w + (size_t)r * 768
                       : (r < 784) ? Bp + (size_t)(r - 768) * 768
                       : (r < 800) ? Cp + (size_t)(r - 784) * 768
                                   : nullptr;
    if (src) {
      *(float4*)(v) = *(const float4*)(src + k8 * 8);
      *(float4*)(v + 4) = *(const float4*)(src + k8 * 8 + 4);
    } else {
#pragma unroll
      for (int e = 0; e < 8; ++e) v[e] = 0.f;
    }
    *(short8*)(w_dbc + tix(r, k8 * 8)) = pack8(v);
    return;
  }
  i -= 896 * 96;
  if (i < 768 * 96) {
    const int r = i / 96, k8 = i - r * 96;
    float v[8];
    *(float4*)(v) = *(const float4*)(out_w + (size_t)r * 768 + k8 * 8);
    *(float4*)(v + 4) = *(const float4*)(out_w + (size_t)r * 768 + k8 * 8 + 4);
    *(short8*)(w_out + tix(r, k8 * 8)) = pack8(v);
    return;
  }
  i -= 768 * 96;
  A2[i] = -expf(A_log[i]) * 1.44269504088896f;  // A * log2(e)
}

// ---------------------------------------------------------------------------
// LDS-FREE GEMM: 128x128 tile, BK=32, 4 waves (2x2), per-wave 64x64.
// Both operands pre-tiled (tix) -> each wave's fragment = contiguous 1KB
// global_load_dwordx4 (L1/L2 vector path; L1 catches the 2x intra-block wave
// sharing).  Register double-buffer: prefetch frags(kt+1) -> barrier (wave
// lockstep for L1 locality) -> 16 MFMA(kt).  Zero LDS; compiler inserts the
// counted vmcnt between load and MFMA automatically.
// MODE 0: in_proj -> tiled-bf16 x_in / tiled-bf16 z, +bias
// MODE 1: dbc     -> tiled-bf16 softplus(delta+bias), f32 B, f32 C
// MODE 2: out_proj-> linear f32 out + bias (d_out)
// ---------------------------------------------------------------------------
template <int MODE>
__global__ __launch_bounds__(256) void gemm128r(
    const char* __restrict__ Amat, const char* __restrict__ Bw,
    const float* __restrict__ bias, void* __restrict__ out0,
    void* __restrict__ out1, void* __restrict__ out2, const int gxn) {
  const int tid  = threadIdx.x;
  const int lane = tid & 63, wave = tid >> 6;
  const int wr = wave >> 1, wc = wave & 1;

  // bijective XCD swizzle; consecutive swz share tm -> A-panel L2 locality
  const int nwg = gridDim.x, id = blockIdx.x;
  const int swz = (id & 7) * (nwg >> 3) + (id >> 3);
  const int tm = swz / gxn, tn = swz - tm * gxn;

  // fragment offsets within one 8KB tile (identical to R9's LDS image)
  const int frow = lane & 15, fq = lane >> 4;
  const int pc = (fq << 4) ^ (((frow >> 1) & 3) << 4);
  const int aoff = ((wr * 64 + frow) << 6) + pc;
  const int boff = ((wc * 64 + frow) << 6) + pc;

  const char* Ab = Amat + (size_t)(tm * 24) * 8192 + aoff;
  const char* Bb = Bw   + (size_t)(tn * 24) * 8192 + boff;

  f32x4 acc[4][4];
#pragma unroll
  for (int m = 0; m < 4; ++m)
#pragma unroll
    for (int n = 0; n < 4; ++n) acc[m][n] = (f32x4){0.f, 0.f, 0.f, 0.f};

  short8 a0[4], b0[4], a1[4], b1[4];
#define LOADF(A, B, kt)                                                         \
  {                                                                             \
    const char* pa = Ab + (kt) * 8192;                                          \
    const char* pb = Bb + (kt) * 8192;                                          \
    _Pragma("unroll") for (int m = 0; m < 4; ++m)                               \
        A[m] = *(const short8*)(pa + m * 1024);                                 \
    _Pragma("unroll") for (int n = 0; n < 4; ++n)                               \
        B[n] = *(const short8*)(pb + n * 1024);                                 \
  }
#define MMA(A, B)                                                               \
  {                                                                             \
    __builtin_amdgcn_s_setprio(1);                                              \
    _Pragma("unroll") for (int m = 0; m < 4; ++m)                               \
    _Pragma("unroll") for (int n = 0; n < 4; ++n)                               \
        acc[m][n] = __builtin_amdgcn_mfma_f32_16x16x32_bf16(A[m], B[n],         \
                                                            acc[m][n], 0, 0, 0);\
    __builtin_amdgcn_s_setprio(0);                                              \
  }

  LOADF(a0, b0, 0);
  for (int kt = 0; kt < 24; kt += 2) {
    LOADF(a1, b1, kt + 1);          // prefetch odd tile
    __builtin_amdgcn_s_barrier();   // wave lockstep (L1 temporal locality)
    MMA(a0, b0);
    if (kt + 2 < 24) LOADF(a0, b0, kt + 2);  // prefetch next even tile
    __builtin_amdgcn_s_barrier();
    MMA(a1, b1);
  }

  // epilogue (C/D layout: col = lane&15, row = (lane>>4)*4 + i)
  const int rowA0 = tm * 128, rowB0 = tn * 128;
#pragma unroll
  for (int m = 0; m < 4; ++m) {
    const int grow0 = rowA0 + wr * 64 + m * 16 + fq * 4;
#pragma unroll
    for (int n = 0; n < 4; ++n) {
      const int gcol = rowB0 + wc * 64 + n * 16 + frow;
#pragma unroll
      for (int i = 0; i < 4; ++i) {
        const int grow = grow0 + i;
        float v = acc[m][n][i];
        if (MODE == 0) {
          v += bias[gcol];
          if (gcol < 768)
            *(short*)((char*)out0 + tix(grow, gcol)) = f2b(v);
          else
            *(short*)((char*)out1 + tix(grow, gcol - 768)) = f2b(v);
        } else if (MODE == 1) {
          if (gcol < 768) {
            v += bias[gcol];
            float sp = (v > 20.f) ? v : log1pf(expf(v));
            *(short*)((char*)out0 + tix(grow, gcol)) = f2b(sp);
          } else if (gcol < 784) {
            ((float*)out1)[(size_t)grow * 16 + (gcol - 768)] = v;
          } else if (gcol < 800) {
            ((float*)out2)[(size_t)grow * 16 + (gcol - 784)] = v;
          }
        } else {
          ((float*)out0)[(size_t)grow * 768 + gcol] = v + bias[gcol];
        }
      }
    }
  }
#undef LOADF
#undef MMA
}

// ---------------------------------------------------------------------------
// Depthwise conv1d (K=3, pad=1) + bias + SiLU, tiled in/out, short8 slots.
// ---------------------------------------------------------------------------
__global__ __launch_bounds__(256) void conv_silu8(
    const char* __restrict__ xin, const float* __restrict__ conv_w,
    const float* __restrict__ conv_b, char* __restrict__ xc) {
  const int idx = blockIdx.x * 256 + threadIdx.x;   // over 16384*96
  const int r  = idx / 96;
  const int d8 = (idx - r * 96) * 8;
  const int t  = r & (SEQL - 1);

  short8 x0 = *(const short8*)(xin + tix(r, d8));
  short8 xm = {}, xp = {};
  if (t > 0)        xm = *(const short8*)(xin + tix(r - 1, d8));
  if (t < SEQL - 1) xp = *(const short8*)(xin + tix(r + 1, d8));

  const float4* cw4 = (const float4*)(conv_w + d8 * 3);  // 24 floats
  float4 cw[6];
#pragma unroll
  for (int q = 0; q < 6; ++q) cw[q] = cw4[q];
  float4 cb0 = *(const float4*)(conv_b + d8);
  float4 cb1 = *(const float4*)(conv_b + d8 + 4);
  const float* cwf = (const float*)cw;
  const float* cbf0 = (const float*)&cb0;
  const float* cbf1 = (const float*)&cb1;

  short8 res;
#pragma unroll
  for (int e = 0; e < 8; ++e) {
    float acc = (e < 4) ? cbf0[e] : cbf1[e - 4];
    acc = fmaf(cwf[e * 3 + 0], b2f(xm[e]), acc);
    acc = fmaf(cwf[e * 3 + 1], b2f(x0[e]), acc);
    acc = fmaf(cwf[e * 3 + 2], b2f(xp[e]), acc);
    const float sig = 1.f / (1.f + __expf(-acc));
    res[e] = f2b(acc * sig);
  }
  *(short8*)(xc + tix(r, d8)) = res;
}

// ---------------------------------------------------------------------------
// Scan pass 1: per (b, d, chunk) local scan with h_in = 0.
// tb = tile-base + row-base only; slot(t) = (sd0 ^ (t>>1)) & 3 (r0 64-aligned).
// ---------------------------------------------------------------------------
__global__ __launch_bounds__(256) void scan_pass1(
    const char* __restrict__ delta, const char* __restrict__ xconv,
    const float* __restrict__ Bsel, const float* __restrict__ A2,
    float* __restrict__ sumdt, float* __restrict__ Sbuf) {
  const int d = blockIdx.x * 256 + threadIdx.x;
  const int b = blockIdx.y, c = blockIdx.z;
  __shared__ float sB[TCHUNK * 16];
  ((float4*)sB)[threadIdx.x] =
      ((const float4*)(Bsel + ((size_t)b * SEQL + c * TCHUNK) * 16))[threadIdx.x];
  __syncthreads();

  float a2[16];
#pragma unroll
  for (int n = 0; n < 16; ++n) a2[n] = A2[d * 16 + n];
  float h[16] = {};
  float sdt = 0.f;
  const int r0 = b * SEQL + c * TCHUNK;       // 64-aligned
  const unsigned tb = (((unsigned)((r0 >> 7) * 24 + (d >> 5))) << 13) + ((r0 & 127) << 6);
  const unsigned sd0 = (d >> 3) & 3;
  const unsigned klo = (d & 7) << 1;
  for (int t = 0; t < TCHUNK; ++t) {
    const unsigned ro = tb + t * 64 + (((sd0 ^ ((unsigned)t >> 1)) & 3) << 4) + klo;
    const float dt = b2f(*(const short*)(delta + ro));
    const float x = b2f(*(const short*)(xconv + ro));
    sdt += dt;
    const float dtx = dt * x;
    const float* Br = &sB[t * 16];
#pragma unroll
    for (int n = 0; n < 16; ++n) {
      const float a = exp2f(dt * a2[n]);
      h[n] = fmaf(a, h[n], dtx * Br[n]);
    }
  }
  sumdt[((size_t)b * NCHUNK + c) * 768 + d] = sdt;
#pragma unroll
  for (int n = 0; n < 16; ++n)
    Sbuf[(((size_t)b * NCHUNK + c) * 16 + n) * 768 + d] = h[n];
}

// ---------------------------------------------------------------------------
// Scan pass 2: serial carry over chunks, one thread per (b, n, d) chain.
// ---------------------------------------------------------------------------
__global__ __launch_bounds__(256) void scan_carry(
    const float* __restrict__ sumdt, const float* __restrict__ Sbuf,
    const float* __restrict__ A2, float* __restrict__ Hin) {
  const int idx = blockIdx.x * 256 + threadIdx.x;  // 0..98303
  const int d = idx % 768;
  const int n = (idx / 768) & 15;
  const int b = idx / (768 * 16);
  const float a2 = A2[d * 16 + n];
  float h = 0.f;
  for (int c = 0; c < NCHUNK; ++c) {
    const size_t hb = (((size_t)(b * NCHUNK + c)) * 16 + n) * 768 + d;
    Hin[hb] = h;
    const float sd = sumdt[(b * NCHUNK + c) * 768 + d];
    h = fmaf(exp2f(sd * a2), h, Sbuf[hb]);
  }
}

// ---------------------------------------------------------------------------
// Scan pass 3: replay with correct h_in; fuse D-skip + silu(z) gating.
// ---------------------------------------------------------------------------
__global__ __launch_bounds__(256) void scan_pass3(
    const char* __restrict__ delta, const char* __restrict__ xconv,
    const char* __restrict__ zb, const float* __restrict__ Bsel,
    const float* __restrict__ Csel, const float* __restrict__ A2,
    const float* __restrict__ Hin, const float* __restrict__ Dp,
    char* __restrict__ yg) {
  const int d = blockIdx.x * 256 + threadIdx.x;
  const int b = blockIdx.y, c = blockIdx.z;
  __shared__ float sB[TCHUNK * 16], sC[TCHUNK * 16];
  {
    const size_t off = ((size_t)b * SEQL + c * TCHUNK) * 16;
    ((float4*)sB)[threadIdx.x] = ((const float4*)(Bsel + off))[threadIdx.x];
    ((float4*)sC)[threadIdx.x] = ((const float4*)(Csel + off))[threadIdx.x];
  }
  __syncthreads();

  float a2[16];
#pragma unroll
  for (int n = 0; n < 16; ++n) a2[n] = A2[d * 16 + n];
  float h[16];
  {
    const size_t hb = ((size_t)b * NCHUNK + c) * 16 * 768 + d;
#pragma unroll
    for (int n = 0; n < 16; ++n) h[n] = Hin[hb + (size_t)n * 768];
  }
  const float Dpd = Dp[d];
  const int r0 = b * SEQL + c * TCHUNK;
  const unsigned tb = (((unsigned)((r0 >> 7) * 24 + (d >> 5))) << 13) + ((r0 & 127) << 6);
  const unsigned sd0 = (d >> 3) & 3;
  const unsigned klo = (d & 7) << 1;
  for (int t = 0; t < TCHUNK; ++t) {
    const unsigned ro = tb + t * 64 + (((sd0 ^ ((unsigned)t >> 1)) & 3) << 4) + klo;
    const float dt = b2f(*(const short*)(delta + ro));
    const float x = b2f(*(const short*)(xconv + ro));
    const float dtx = dt * x;
    const float* Br = &sB[t * 16];
    const float* Cr = &sC[t * 16];
    float y = 0.f;
#pragma unroll
    for (int n = 0; n < 16; ++n) {
      const float a = exp2f(dt * a2[n]);
      h[n] = fmaf(a, h[n], dtx * Br[n]);
      y = fmaf(h[n], Cr[n], y);
    }
    const float z = b2f(*(const short*)(zb + ro));
    const float sig = 1.f / (1.f + __expf(-z));
    const float out = (y + x * Dpd) * (z * sig);
    *(short*)(yg + ro) = f2b(out);
  }
}

// ---------------------------------------------------------------------------
// Launch
// ---------------------------------------------------------------------------
extern "C" void kernel_launch(void* const* d_in, const int* in_sizes, int n_in,
                              void* d_out, int out_size, void* d_ws, size_t ws_size,
                              hipStream_t stream) {
  const float* x       = (const float*)d_in[0];
  const float* A_log   = (const float*)d_in[1];
  const float* D_param = (const float*)d_in[2];
  const float* B_proj  = (const float*)d_in[3];
  const float* C_proj  = (const float*)d_in[4];
  const float* delta_w = (const float*)d_in[5];
  const float* delta_b = (const float*)d_in[6];
  const float* in_w    = (const float*)d_in[7];
  const float* in_b    = (const float*)d_in[8];
  const float* out_w   = (const float*)d_in[9];
  const float* out_b   = (const float*)d_in[10];
  const float* conv_w  = (const float*)d_in[11];
  const float* conv_b  = (const float*)d_in[12];

  char* ws = (char*)d_ws;
  char*  xb       = ws + 0;            // tiled bf16 [16384][768]; reused as yg
  char*  w_in_b   = ws + 25165824;     // tiled bf16 [1536][768]
  char*  w_dbc_b  = ws + 27525120;     // tiled bf16 [896][768]
  char*  w_out_b  = ws + 28901376;     // tiled bf16 [768][768]
  float* A2       = (float*)(ws + 30081024);
  char*  xin_b    = ws + 30130176;     // tiled bf16
  char*  z_b      = ws + 55296000;     // tiled bf16
  char*  xconv_b  = ws + 80461824;     // tiled bf16
  char*  delta_bf = ws + 105627648;    // tiled bf16
  float* Bsel     = (float*)(ws + 130793472);
  float* Csel     = (float*)(ws + 131842048);
  float* sumdt    = (float*)(ws + 132890624);
  float* Sbuf     = (float*)(ws + 133677056);
  float* Hin      = (float*)(ws + 146259968);
  char*  yg       = xb;  // x (bf16) dead after in_proj GEMM

  // 1. prep: x->tiled bf16, weights->tiled bf16, A2
  prep_all<<<7392, 256, 0, stream>>>(x, in_w, delta_w, B_proj, C_proj, out_w, A_log,
                                     xb, w_in_b, w_dbc_b, w_out_b, A2);
  // 2. in_proj GEMM [16384,1536] : 128 x 12 tiles = 1536 blocks
  gemm128r<0><<<1536, 256, 0, stream>>>(xb, w_in_b, in_b, xin_b, z_b, nullptr, 12);
  // 3. depthwise conv + silu (tiled short8)
  conv_silu8<<<16384 * 96 / 256, 256, 0, stream>>>(xin_b, conv_w, conv_b, xconv_b);
  // 4. delta/B/C GEMM [16384,896] : 128 x 7 tiles = 896 blocks
  gemm128r<1><<<896, 256, 0, stream>>>(xconv_b, w_dbc_b, delta_b, delta_bf, Bsel, Csel, 7);
  // 5-7. chunked scan
  scan_pass1<<<dim3(3, BATCH, NCHUNK), 256, 0, stream>>>(delta_bf, xconv_b, Bsel, A2, sumdt, Sbuf);
  scan_carry<<<384, 256, 0, stream>>>(sumdt, Sbuf, A2, Hin);
  scan_pass3<<<dim3(3, BATCH, NCHUNK), 256, 0, stream>>>(delta_bf, xconv_b, z_b, Bsel, Csel, A2,
                                                         Hin, D_param, yg);
  // 8. out_proj GEMM [16384,768] : 128 x 6 tiles = 768 blocks
  gemm128r<2><<<768, 256, 0, stream>>>(yg, w_out_b, out_b, (float*)d_out, nullptr, nullptr, 6);
}